// Round 5
// baseline (117.298 us; speedup 1.0000x reference)
//
#include <hip/hip_runtime.h>
#include <math.h>

#define NCODES 16
#define NHALF 8
#define LOG2E 1.4426950408889634f

typedef float f32x4 __attribute__((ext_vector_type(4)));

// Force a wave-uniform float into an SGPR (exact: value identical on all lanes).
__device__ __forceinline__ float rfl(float v) {
    return __int_as_float(__builtin_amdgcn_readfirstlane(__float_as_int(v)));
}

// ThermoQuantizer: per-128-group abs-mean scale, soft-quantize to uniform
// 16-level codebook via softmax over -(x_norm-c)^2/T, lerp with pressure.
//
// Algebraic collapse (codebook = linspace(-1,1,16), uniform & symmetric):
//   prob_i ∝ exp((2 x c_i - c_i^2)/T)  (x^2 term cancels in softmax)
// For x>=0, with codes C_j = cb[15-j] (descending from +1):
//   term_j = W_j * q^j,  W_j = exp(-C_j^2/T),  q = exp(-2|xn|*step/T) in (0,1]
// Even/odd Horner split in q2: num = En(q2)+q*On(q2), den = Ed(q2)+q*Od(q2).
// x<0 by odd symmetry (copysign).
//
// Ladder: v1 (32x1 lanes, VGPR tables) ~32.3us kernel. R1: LDS-LUT regressed
// (gather conflicts). R2: SGPR tables + FORCED launch_bounds(256,8) + far
// unroll regressed (64-VGPR cap -> spills). v4: 16 lanes x 2 float4 (MLP=2,
// 4-step reduce) -> 30.4us kernel / 115.8us total. VALU issue is only ~8us
// chip-wide; HBM floor 21.3us; residual = latency-hiding depth at 4
// waves/SIMD (65-128 VGPR band, ~32 of which are wave-uniform coefficients).
//
// v5 = v4 + coefficient tables in SGPRs via readfirstlane (exact - uniform
// values), NO forced occupancy. Each fma reads <=1 SGPR (legal). Drops ~32
// VGPRs -> aims for the <=64-VGPR / 8-waves-per-SIMD band naturally.
// (R4 was an infra failure - container acquisition; resubmitting unchanged.)
__global__ __launch_bounds__(256) void tq_kernel(
    const float* __restrict__ x,
    const float* __restrict__ cb,
    const float* __restrict__ pp,
    const float* __restrict__ tp,
    float* __restrict__ out,
    int n4)
{
    const float pressure = rfl(pp[0]);
    const float invT = rfl(1.0f / (tp[0] + 1e-6f));

    // Per-wave code tables in SGPRs (even/odd in power index j). j-th code
    // (for x>=0): C_j = cb[15-j].
    float WE[NHALF], WO[NHALF], WCE[NHALF], WCO[NHALF];
#pragma unroll
    for (int h = 0; h < NHALF; ++h) {
        float ce = rfl(cb[NCODES - 1 - 2 * h]);   // j = 2h
        float co = rfl(cb[NCODES - 2 - 2 * h]);   // j = 2h+1
        float we = exp2f(-ce * ce * invT * LOG2E);
        float wo = exp2f(-co * co * invT * LOG2E);
        WE[h] = rfl(we);  WCE[h] = rfl(we * ce);
        WO[h] = rfl(wo);  WCO[h] = rfl(wo * co);
    }
    const float step = rfl((cb[NCODES - 1] - cb[0]) * (1.0f / 15.0f));
    const float kq = rfl(2.0f * step * invT * LOG2E);  // q = exp2(-|xn| * kq)

    // Soft-quantize one float4 given the group stats.
    auto process = [&](f32x4 v, float mean_c, float inv_mean) -> f32x4 {
        f32x4 o;
#pragma unroll
        for (int e = 0; e < 4; ++e) {
            float xv = v[e];
            float xn = fabsf(xv) * inv_mean;
            float q  = exp2f(-xn * kq);
            float q2 = q * q;
            // 4 independent Horner chains of 7 fmas each (SGPR coefficients).
            float en = WCE[NHALF - 1], on = WCO[NHALF - 1];
            float ed = WE[NHALF - 1],  od = WO[NHALF - 1];
#pragma unroll
            for (int h = NHALF - 2; h >= 0; --h) {
                en = fmaf(en, q2, WCE[h]);
                on = fmaf(on, q2, WCO[h]);
                ed = fmaf(ed, q2, WE[h]);
                od = fmaf(od, q2, WO[h]);
            }
            float num = fmaf(q, on, en);
            float den = fmaf(q, od, ed);
            float qn = num * __builtin_amdgcn_rcpf(den);  // qx_norm for |x|
            qn = copysignf(qn, xv);                        // odd symmetry
            float qx = qn * mean_c;                        // un-normalize
            o[e] = fmaf(pressure, qx - xv, xv);            // lerp
        }
        return o;
    };

    // Group = 128 floats = 32 float4s = 16 lanes x 2 float4s.
    const int tid     = blockIdx.x * blockDim.x + threadIdx.x;
    const int lane16  = threadIdx.x & 15;
    const int ngroups = n4 >> 5;                          // 32 float4 / group
    const int gstride = (gridDim.x * blockDim.x) >> 4;    // groups per pass

    for (int g = tid >> 4; g < ngroups; g += gstride) {
        const int base = g * 32 + lane16;
        // Two independent 16B loads, 256B apart -> MLP=2 per lane.
        f32x4 va = reinterpret_cast<const f32x4*>(x)[base];
        f32x4 vb = reinterpret_cast<const f32x4*>(x)[base + 16];

        float a = fabsf(va.x) + fabsf(va.y) + fabsf(va.z) + fabsf(va.w)
                + fabsf(vb.x) + fabsf(vb.y) + fabsf(vb.z) + fabsf(vb.w);
#pragma unroll
        for (int m = 1; m <= 8; m <<= 1)
            a += __shfl_xor(a, m, 64);   // masks <16: stays within 16 lanes

        const float mean_c   = fmaxf(a * (1.0f / 128.0f), 1e-5f);
        const float inv_mean = __builtin_amdgcn_rcpf(mean_c);

        f32x4 oa = process(va, mean_c, inv_mean);
        f32x4 ob = process(vb, mean_c, inv_mean);
        __builtin_nontemporal_store(oa, reinterpret_cast<f32x4*>(out) + base);
        __builtin_nontemporal_store(ob, reinterpret_cast<f32x4*>(out) + base + 16);
    }
}

extern "C" void kernel_launch(void* const* d_in, const int* in_sizes, int n_in,
                              void* d_out, int out_size, void* d_ws, size_t ws_size,
                              hipStream_t stream)
{
    const float* x  = (const float*)d_in[0];
    const float* cb = (const float*)d_in[1];
    const float* pp = (const float*)d_in[2];  // pressure (1-elem array)
    const float* tp = (const float*)d_in[3];  // temp (1-elem array)
    float* out = (float*)d_out;

    int n4 = in_sizes[0] / 4;   // 4194304 float4s; multiple of 32 => groups align
    dim3 grid(2048), block(256);
    hipLaunchKernelGGL(tq_kernel, grid, block, 0, stream,
                       x, cb, pp, tp, out, n4);
}

// Round 6
// 116.494 us; speedup vs baseline: 1.0069x; 1.0069x over previous
//
#include <hip/hip_runtime.h>
#include <math.h>

#define NCODES 16
#define NHALF 8
#define LOG2E 1.4426950408889634f

typedef float f32x4 __attribute__((ext_vector_type(4)));

// Force a wave-uniform float into an SGPR (exact: value identical on all lanes).
__device__ __forceinline__ float rfl(float v) {
    return __int_as_float(__builtin_amdgcn_readfirstlane(__float_as_int(v)));
}

// ThermoQuantizer: per-128-group abs-mean scale, soft-quantize to uniform
// 16-level codebook via softmax over -(x_norm-c)^2/T, lerp with pressure.
//
// Algebraic collapse (codebook = linspace(-1,1,16), uniform & symmetric):
//   prob_i ∝ exp((2 x c_i - c_i^2)/T)  (x^2 term cancels in softmax)
// For x>=0, with codes C_j = cb[15-j] (descending from +1):
//   term_j = W_j * q^j,  W_j = exp(-C_j^2/T),  q = exp(-2|xn|*step/T) in (0,1]
// Even/odd Horner split in q2: num = En(q2)+q*On(q2), den = Ed(q2)+q*Od(q2).
// x<0 by odd symmetry (copysign).
//
// Ladder: v1 32.3us. R1 LDS-LUT regressed (gather conflicts). R2 forced
// launch_bounds(256,8) regressed (spills). v4 16-lane x 2-float4 (MLP=2):
// 30.4us. v5 = v4 + SGPR coeff tables: VGPR=40 (measured), ~29.3us, neutral
// -> occupancy-via-VGPR exonerated. R5 counters: hbm_bytes only 100MB (L3
// serves half the reads -> floor ~16us), VALUBusy 40%, hbm ~3.4TB/s eff,
// occupancy 46% -- BOTH pipes half-idle = latency-bound on the serial
// load->4xshuffle(~500cy)->800cy-VALU chain, MLP=2, one chain per wave.
//
// v6: use the 24 freed VGPRs. Each 16-lane cluster handles TWO adjacent
// groups per iter: 4 back-to-back dwordx4 (1KiB contiguous/cluster), then
// two INDEPENDENT reduce->Horner->store chains (B's shuffles hide under A's
// VALU). Per-group math/reduce order bit-identical to v5. Live state ~56
// VGPR -> stays in the <=64 / 8-waves-per-SIMD band (verify VGPR_Count!).
__global__ __launch_bounds__(256) void tq_kernel(
    const float* __restrict__ x,
    const float* __restrict__ cb,
    const float* __restrict__ pp,
    const float* __restrict__ tp,
    float* __restrict__ out,
    int n4)
{
    const float pressure = rfl(pp[0]);
    const float invT = rfl(1.0f / (tp[0] + 1e-6f));

    // Per-wave code tables in SGPRs (even/odd in power index j). j-th code
    // (for x>=0): C_j = cb[15-j].
    float WE[NHALF], WO[NHALF], WCE[NHALF], WCO[NHALF];
#pragma unroll
    for (int h = 0; h < NHALF; ++h) {
        float ce = rfl(cb[NCODES - 1 - 2 * h]);   // j = 2h
        float co = rfl(cb[NCODES - 2 - 2 * h]);   // j = 2h+1
        float we = exp2f(-ce * ce * invT * LOG2E);
        float wo = exp2f(-co * co * invT * LOG2E);
        WE[h] = rfl(we);  WCE[h] = rfl(we * ce);
        WO[h] = rfl(wo);  WCO[h] = rfl(wo * co);
    }
    const float step = rfl((cb[NCODES - 1] - cb[0]) * (1.0f / 15.0f));
    const float kq = rfl(2.0f * step * invT * LOG2E);  // q = exp2(-|xn| * kq)

    // Soft-quantize one float4 given the group stats.
    auto process = [&](f32x4 v, float mean_c, float inv_mean) -> f32x4 {
        f32x4 o;
#pragma unroll
        for (int e = 0; e < 4; ++e) {
            float xv = v[e];
            float xn = fabsf(xv) * inv_mean;
            float q  = exp2f(-xn * kq);
            float q2 = q * q;
            // 4 independent Horner chains of 7 fmas each (SGPR coefficients).
            float en = WCE[NHALF - 1], on = WCO[NHALF - 1];
            float ed = WE[NHALF - 1],  od = WO[NHALF - 1];
#pragma unroll
            for (int h = NHALF - 2; h >= 0; --h) {
                en = fmaf(en, q2, WCE[h]);
                on = fmaf(on, q2, WCO[h]);
                ed = fmaf(ed, q2, WE[h]);
                od = fmaf(od, q2, WO[h]);
            }
            float num = fmaf(q, on, en);
            float den = fmaf(q, od, ed);
            float qn = num * __builtin_amdgcn_rcpf(den);  // qx_norm for |x|
            qn = copysignf(qn, xv);                        // odd symmetry
            float qx = qn * mean_c;                        // un-normalize
            o[e] = fmaf(pressure, qx - xv, xv);            // lerp
        }
        return o;
    };

    auto asum = [](f32x4 u, f32x4 w) -> float {
        return fabsf(u.x) + fabsf(u.y) + fabsf(u.z) + fabsf(u.w)
             + fabsf(w.x) + fabsf(w.y) + fabsf(w.z) + fabsf(w.w);
    };

    // Group = 128 floats = 32 float4s = 16 lanes x 2 float4s.
    // Each cluster processes a PAIR of adjacent groups per iteration.
    const int tid     = blockIdx.x * blockDim.x + threadIdx.x;
    const int lane16  = threadIdx.x & 15;
    const int cluster = tid >> 4;
    const int nclust  = (gridDim.x * blockDim.x) >> 4;
    const int ngroups = n4 >> 5;                 // 32 float4 / group
    const int npairs  = ngroups >> 1;

    const f32x4* xp = reinterpret_cast<const f32x4*>(x);
    f32x4*       op = reinterpret_cast<f32x4*>(out);

    for (int p = cluster; p < npairs; p += nclust) {
        const int base = p * 64 + lane16;
        // Four independent 16B loads, back-to-back: 1KiB contiguous/cluster.
        f32x4 va0 = xp[base];
        f32x4 vb0 = xp[base + 16];
        f32x4 va1 = xp[base + 32];
        f32x4 vb1 = xp[base + 48];

        float a0 = asum(va0, vb0);
        float a1 = asum(va1, vb1);
#pragma unroll
        for (int m = 1; m <= 8; m <<= 1) {       // masks <16: within 16 lanes
            a0 += __shfl_xor(a0, m, 64);
            a1 += __shfl_xor(a1, m, 64);
        }
        const float mean0 = fmaxf(a0 * (1.0f / 128.0f), 1e-5f);
        const float mean1 = fmaxf(a1 * (1.0f / 128.0f), 1e-5f);
        const float inv0  = __builtin_amdgcn_rcpf(mean0);
        const float inv1  = __builtin_amdgcn_rcpf(mean1);

        f32x4 oa0 = process(va0, mean0, inv0);
        __builtin_nontemporal_store(oa0, op + base);
        f32x4 ob0 = process(vb0, mean0, inv0);
        __builtin_nontemporal_store(ob0, op + base + 16);
        f32x4 oa1 = process(va1, mean1, inv1);
        __builtin_nontemporal_store(oa1, op + base + 32);
        f32x4 ob1 = process(vb1, mean1, inv1);
        __builtin_nontemporal_store(ob1, op + base + 48);
    }

    // Tail: odd final group (not hit for 4096x4096, kept for generality).
    for (int g = npairs * 2 + cluster; g < ngroups; g += nclust) {
        const int base = g * 32 + lane16;
        f32x4 va = xp[base];
        f32x4 vb = xp[base + 16];
        float a = asum(va, vb);
#pragma unroll
        for (int m = 1; m <= 8; m <<= 1)
            a += __shfl_xor(a, m, 64);
        const float mean_c   = fmaxf(a * (1.0f / 128.0f), 1e-5f);
        const float inv_mean = __builtin_amdgcn_rcpf(mean_c);
        f32x4 oa = process(va, mean_c, inv_mean);
        f32x4 ob = process(vb, mean_c, inv_mean);
        __builtin_nontemporal_store(oa, op + base);
        __builtin_nontemporal_store(ob, op + base + 16);
    }
}

extern "C" void kernel_launch(void* const* d_in, const int* in_sizes, int n_in,
                              void* d_out, int out_size, void* d_ws, size_t ws_size,
                              hipStream_t stream)
{
    const float* x  = (const float*)d_in[0];
    const float* cb = (const float*)d_in[1];
    const float* pp = (const float*)d_in[2];  // pressure (1-elem array)
    const float* tp = (const float*)d_in[3];  // temp (1-elem array)
    float* out = (float*)d_out;

    int n4 = in_sizes[0] / 4;   // 4194304 float4s; multiple of 32 => groups align
    dim3 grid(2048), block(256);
    hipLaunchKernelGGL(tq_kernel, grid, block, 0, stream,
                       x, cb, pp, tp, out, n4);
}